// Round 4
// baseline (1035.962 us; speedup 1.0000x reference)
//
#include <hip/hip_runtime.h>
#include <hip/hip_bf16.h>

typedef __attribute__((ext_vector_type(8))) short short8;
typedef __attribute__((ext_vector_type(8))) unsigned short ushort8;
typedef __attribute__((ext_vector_type(4))) float f32x4;

#define EPSN 1e-12f
#define GN 1024
#define GK 512

__device__ __forceinline__ float bf2f(unsigned short h) {
  union { unsigned int u; float f; } c; c.u = ((unsigned int)h) << 16; return c.f;
}
__device__ __forceinline__ unsigned short f2bf(float f) {
  union { float f; unsigned int u; } c; c.f = f;
  unsigned int u = c.u;
  return (unsigned short)((u + 0x7fffu + ((u >> 16) & 1u)) >> 16);
}
__device__ __forceinline__ float wredsum(float v) {
  v += __shfl_xor(v, 32); v += __shfl_xor(v, 16); v += __shfl_xor(v, 8);
  v += __shfl_xor(v, 4);  v += __shfl_xor(v, 2);  v += __shfl_xor(v, 1);
  return v;
}

#define GLL(g, l) __builtin_amdgcn_global_load_lds( \
    (const __attribute__((address_space(1))) unsigned int*)(g), \
    (__attribute__((address_space(3))) unsigned int*)(l), 16, 0, 0)

// ---------------- prep: normalize positive_center (1 row) + negative_centers (4 rows)
__global__ void k_prep(const float* __restrict__ pc, const float* __restrict__ nc,
                       float* __restrict__ pos_hat, float* __restrict__ negc0_hat) {
  int tid = threadIdx.x, lane = tid & 63, w = tid >> 6; // 5 waves
  const float* src = (w == 0) ? pc : (nc + (w - 1) * 512);
  float* dst = (w == 0) ? pos_hat : (negc0_hat + (w - 1) * 512);
  float4 a = *(const float4*)(src + lane * 8);
  float4 b = *(const float4*)(src + lane * 8 + 4);
  float x[8] = {a.x,a.y,a.z,a.w,b.x,b.y,b.z,b.w};
  float ss = 0.f;
  #pragma unroll
  for (int j = 0; j < 8; j++) ss += x[j]*x[j];
  ss = wredsum(ss);
  float inv = 1.f / fmaxf(sqrtf(ss), EPSN);
  #pragma unroll
  for (int j = 0; j < 8; j++) dst[lane*8+j] = x[j]*inv;
}

// ---------------- row norms: write RAW bf16 cast + 1/||row|| (wave per row, grid-stride)
__global__ __launch_bounds__(256) void k_rownorm(const float* __restrict__ X,
                                                 unsigned short* __restrict__ Y,
                                                 float* __restrict__ invn, int rows) {
  int lane = threadIdx.x & 63;
  int w0 = blockIdx.x * 4 + (threadIdx.x >> 6);
  int nw = gridDim.x * 4;
  for (int row = w0; row < rows; row += nw) {
    const float* src = X + (size_t)row * 512 + lane * 8;
    float4 a = *(const float4*)src;
    float4 b = *(const float4*)(src + 4);
    float x[8] = {a.x,a.y,a.z,a.w,b.x,b.y,b.z,b.w};
    float ss = 0.f;
    #pragma unroll
    for (int j = 0; j < 8; j++) ss += x[j]*x[j];
    ss = wredsum(ss);
    float inv = 1.f / fmaxf(sqrtf(ss), EPSN);
    if (lane == 0) invn[row] = inv;
    ushort8 o;
    #pragma unroll
    for (int j = 0; j < 8; j++) o[j] = f2bf(x[j]);   // RAW cast; normalization applied in GEMM epilogue
    *(ushort8*)(Y + (size_t)row * 512 + lane * 8) = o;
  }
}

// ---------------- l_loss: accumulate sum of pos_hat . norm(p_feats_row)
__global__ __launch_bounds__(256) void k_ploss(const float* __restrict__ PF, const float* __restrict__ ph_g,
                                               float* __restrict__ scal) {
  __shared__ float lred[4];
  int tid = threadIdx.x, lane = tid & 63, w = tid >> 6;
  float ph[8];
  #pragma unroll
  for (int j = 0; j < 8; j++) ph[j] = ph_g[lane*8+j];
  float lsum = 0.f;
  int row0 = blockIdx.x * 256;
  for (int rr = w; rr < 256; rr += 4) {
    int row = row0 + rr;
    const float* src = PF + (size_t)row * 512 + lane * 8;
    float4 a = *(const float4*)src;
    float4 b = *(const float4*)(src + 4);
    float x[8] = {a.x,a.y,a.z,a.w,b.x,b.y,b.z,b.w};
    float ss = 0.f, dp = 0.f;
    #pragma unroll
    for (int j = 0; j < 8; j++) { ss += x[j]*x[j]; dp += x[j]*ph[j]; }
    ss = wredsum(ss); dp = wredsum(dp);
    if (lane == 0) lsum += dp / fmaxf(sqrtf(ss), EPSN);
  }
  if (lane == 0) lred[w] = lsum;
  __syncthreads();
  if (tid == 0) atomicAdd(&scal[0], lred[0]+lred[1]+lred[2]+lred[3]);
}

// ---------------- n_feats pass 1: inv norms, keep/argmax, cluster counts + raw sums
__global__ __launch_bounds__(256) void k_nstats(const float* __restrict__ NF, const float* __restrict__ ph_g,
                                                const float* __restrict__ nch0, float* __restrict__ inv_n,
                                                float* __restrict__ counts, float* __restrict__ sums) {
  __shared__ float fl[8192]; // [4 waves][4][512]
  int tid = threadIdx.x, lane = tid & 63, w = tid >> 6;
  float ph[8], nh[4][8];
  #pragma unroll
  for (int j = 0; j < 8; j++) ph[j] = ph_g[lane*8+j];
  #pragma unroll
  for (int c = 0; c < 4; c++)
    #pragma unroll
    for (int j = 0; j < 8; j++) nh[c][j] = nch0[c*512 + lane*8 + j];
  float acc[4][8];
  float cnt[4] = {0.f,0.f,0.f,0.f};
  #pragma unroll
  for (int c = 0; c < 4; c++)
    #pragma unroll
    for (int j = 0; j < 8; j++) acc[c][j] = 0.f;
  int row0 = blockIdx.x * 256;
  for (int rr = w; rr < 256; rr += 4) {
    int row = row0 + rr;
    const float* src = NF + (size_t)row * 512 + lane * 8;
    float4 a = *(const float4*)src;
    float4 b = *(const float4*)(src + 4);
    float x[8] = {a.x,a.y,a.z,a.w,b.x,b.y,b.z,b.w};
    float ss = 0.f, dp = 0.f, dn[4] = {0.f,0.f,0.f,0.f};
    #pragma unroll
    for (int j = 0; j < 8; j++) {
      ss += x[j]*x[j]; dp += x[j]*ph[j];
      #pragma unroll
      for (int c = 0; c < 4; c++) dn[c] += x[j]*nh[c][j];
    }
    ss = wredsum(ss); dp = wredsum(dp);
    #pragma unroll
    for (int c = 0; c < 4; c++) dn[c] = wredsum(dn[c]);
    float inv = 1.f / fmaxf(sqrtf(ss), EPSN);
    if (lane == 0) inv_n[row] = inv;
    float sp = dp * inv;
    float s0 = dn[0]*inv, s1 = dn[1]*inv, s2 = dn[2]*inv, s3 = dn[3]*inv;
    int am = 0; float best = s0;
    if (s1 > best) { best = s1; am = 1; }
    if (s2 > best) { best = s2; am = 2; }
    if (s3 > best) { best = s3; am = 3; }
    float kf = (sp < 0.7f) ? 1.f : 0.f;
    #pragma unroll
    for (int c = 0; c < 4; c++) {
      float m = (am == c) ? kf : 0.f;
      #pragma unroll
      for (int j = 0; j < 8; j++) acc[c][j] += m * x[j];
      if (lane == 0) cnt[c] += m;
    }
  }
  #pragma unroll
  for (int c = 0; c < 4; c++)
    #pragma unroll
    for (int j = 0; j < 8; j++) fl[w*2048 + c*512 + lane*8 + j] = acc[c][j];
  __syncthreads();
  for (int q = tid; q < 2048; q += 256) {
    float t = fl[q] + fl[2048+q] + fl[4096+q] + fl[6144+q];
    atomicAdd(&sums[q], t);
  }
  if (lane == 0) {
    #pragma unroll
    for (int c = 0; c < 4; c++) atomicAdd(&counts[c], cnt[c]);
  }
}

// ---------------- center update + repulsion (single block, wave per cluster)
__global__ void k_center(const float* __restrict__ counts, const float* __restrict__ sums,
                         const float* __restrict__ negc_raw, const float* __restrict__ pos_hat,
                         float* __restrict__ negc_hat, float* __restrict__ scal) {
  __shared__ float hbuf[2048];
  __shared__ float spn[4];
  __shared__ float snn[16];
  int tid = threadIdx.x, lane = tid & 63, c = tid >> 6;
  float cnt = counts[c];
  float x[8], raw[8], ph[8];
  #pragma unroll
  for (int j = 0; j < 8; j++) {
    x[j] = sums[c*512 + lane*8 + j] / fmaxf(cnt, 1.f);
    raw[j] = negc_raw[c*512 + lane*8 + j];
    ph[j] = pos_hat[lane*8 + j];
  }
  float ss = 0.f;
  #pragma unroll
  for (int j = 0; j < 8; j++) ss += x[j]*x[j];
  ss = wredsum(ss);
  float n1 = fmaxf(sqrtf(ss), EPSN);
  #pragma unroll
  for (int j = 0; j < 8; j++) x[j] = raw[j] + (x[j]/n1 - raw[j]) * 0.1f; // lerp (1-momentum)
  ss = 0.f;
  #pragma unroll
  for (int j = 0; j < 8; j++) ss += x[j]*x[j];
  ss = wredsum(ss);
  float n2 = fmaxf(sqrtf(ss), EPSN);
  bool upd = (cnt >= 3.0f);
  #pragma unroll
  for (int j = 0; j < 8; j++) x[j] = upd ? (x[j]/n2) : raw[j];  // selected negc
  ss = 0.f;
  #pragma unroll
  for (int j = 0; j < 8; j++) ss += x[j]*x[j];
  ss = wredsum(ss);
  float n3 = fmaxf(sqrtf(ss), EPSN);
  float dp = 0.f;
  #pragma unroll
  for (int j = 0; j < 8; j++) {
    x[j] = x[j] / n3;                       // negc_hat
    negc_hat[c*512 + lane*8 + j] = x[j];
    hbuf[c*512 + lane*8 + j] = x[j];
    dp += x[j] * ph[j];
  }
  dp = wredsum(dp);
  if (lane == 0) spn[c] = dp;
  __syncthreads();
  float d4[4] = {0.f,0.f,0.f,0.f};
  #pragma unroll
  for (int c2 = 0; c2 < 4; c2++) {
    float d = 0.f;
    #pragma unroll
    for (int j = 0; j < 8; j++) d += x[j] * hbuf[c2*512 + lane*8 + j];
    d4[c2] = wredsum(d);
  }
  if (lane == 0) {
    #pragma unroll
    for (int c2 = 0; c2 < 4; c2++) snn[c*4 + c2] = d4[c2];
  }
  __syncthreads();
  if (tid == 0) {
    float rep_np = 0.f;
    for (int i = 0; i < 4; i++) rep_np += logf(fmaxf(1.f - spn[i], 1e-6f));
    rep_np = -rep_np * 0.25f;
    float rep_nn = 0.f;
    for (int i = 0; i < 4; i++)
      for (int j2 = 0; j2 < 4; j2++)
        if (i != j2) rep_nn += logf(fmaxf(1.f - snn[i*4+j2], 1e-6f));
    rep_nn = -rep_nn / 12.f;
    scal[4] = rep_np + 0.1f * rep_nn;
  }
}

// ---------------- loss_n: softmax self-distill entropy vs updated centers
__global__ __launch_bounds__(256) void k_nloss(const float* __restrict__ NF, const float* __restrict__ inv_n,
                                               const float* __restrict__ nch, float* __restrict__ scal) {
  __shared__ float lred[4];
  int tid = threadIdx.x, lane = tid & 63, w = tid >> 6;
  float nh[4][8];
  #pragma unroll
  for (int c = 0; c < 4; c++)
    #pragma unroll
    for (int j = 0; j < 8; j++) nh[c][j] = nch[c*512 + lane*8 + j];
  float lsum = 0.f;
  int row0 = blockIdx.x * 256;
  for (int rr = w; rr < 256; rr += 4) {
    int row = row0 + rr;
    const float* src = NF + (size_t)row * 512 + lane * 8;
    float4 a = *(const float4*)src;
    float4 b = *(const float4*)(src + 4);
    float x[8] = {a.x,a.y,a.z,a.w,b.x,b.y,b.z,b.w};
    float dn[4] = {0.f,0.f,0.f,0.f};
    #pragma unroll
    for (int j = 0; j < 8; j++)
      #pragma unroll
      for (int c = 0; c < 4; c++) dn[c] += x[j]*nh[c][j];
    #pragma unroll
    for (int c = 0; c < 4; c++) dn[c] = wredsum(dn[c]);
    if (lane == 0) {
      float inv = inv_n[row];
      float s0 = dn[0]*inv, s1 = dn[1]*inv, s2 = dn[2]*inv, s3 = dn[3]*inv;
      float mx = fmaxf(fmaxf(s0,s1), fmaxf(s2,s3));
      float e0 = __expf(s0-mx), e1 = __expf(s1-mx), e2 = __expf(s2-mx), e3 = __expf(s3-mx);
      float Z = e0+e1+e2+e3;
      lsum += (mx + logf(Z)) - (e0*s0+e1*s1+e2*s2+e3*s3)/Z;
    }
  }
  if (lane == 0) lred[w] = lsum;
  __syncthreads();
  if (tid == 0) atomicAdd(&scal[1], lred[0]+lred[1]+lred[2]+lred[3]);
}

// ---------------- u_feats pass: sim_u_neg (normalized) + pseudo rowsum1
__global__ __launch_bounds__(256) void k_upass(const float* __restrict__ U, const float* __restrict__ nch,
                                               float* __restrict__ SU, float* __restrict__ R1p) {
  int tid = threadIdx.x, lane = tid & 63, w = tid >> 6;
  float nh[4][8];
  #pragma unroll
  for (int c = 0; c < 4; c++)
    #pragma unroll
    for (int j = 0; j < 8; j++) nh[c][j] = nch[c*512 + lane*8 + j];
  float eacc[4] = {0.f,0.f,0.f,0.f};
  int row0 = blockIdx.x * 256;
  for (int rr = w; rr < 256; rr += 4) {
    int row = row0 + rr;
    const float* src = U + (size_t)row * 512 + lane * 8;
    float4 a = *(const float4*)src;
    float4 b = *(const float4*)(src + 4);
    float x[8] = {a.x,a.y,a.z,a.w,b.x,b.y,b.z,b.w};
    float ss = 0.f, dn[4] = {0.f,0.f,0.f,0.f};
    #pragma unroll
    for (int j = 0; j < 8; j++) {
      ss += x[j]*x[j];
      #pragma unroll
      for (int c = 0; c < 4; c++) dn[c] += x[j]*nh[c][j];
    }
    ss = wredsum(ss);
    #pragma unroll
    for (int c = 0; c < 4; c++) dn[c] = wredsum(dn[c]);
    float inv = 1.f / fmaxf(sqrtf(ss), EPSN);
    if (lane == 0) {
      float4 sv; sv.x = dn[0]*inv; sv.y = dn[1]*inv; sv.z = dn[2]*inv; sv.w = dn[3]*inv;
      *(float4*)(SU + (size_t)row * 4) = sv;
      eacc[0] += __expf(20.f*sv.x); eacc[1] += __expf(20.f*sv.y);
      eacc[2] += __expf(20.f*sv.z); eacc[3] += __expf(20.f*sv.w);
    }
  }
  if (lane == 0) {
    #pragma unroll
    for (int c = 0; c < 4; c++) atomicAdd(&R1p[c], eacc[c]);
  }
}

// ---------------- pseudo sinkhorn pass over [65536][4] f32
// state Rin[k] = sum_b rawexp[b,k] * g[b]; mode1: accumulate Rout[k] += rawexp*cf ; mode2: loss
__global__ __launch_bounds__(256) void k_psink(const float* __restrict__ SU, const float* __restrict__ Rin,
                                               float* __restrict__ Rout, float* __restrict__ lossAcc, int mode) {
  float r0 = 1.f/(4.f*Rin[0]), r1 = 1.f/(4.f*Rin[1]), r2 = 1.f/(4.f*Rin[2]), r3 = 1.f/(4.f*Rin[3]);
  float a0 = 0.f, a1 = 0.f, a2 = 0.f, a3 = 0.f, lsum = 0.f;
  int stride = gridDim.x * blockDim.x;
  for (int row = blockIdx.x * blockDim.x + threadIdx.x; row < 65536; row += stride) {
    float4 s = *(const float4*)(SU + (size_t)row * 4);
    float x0 = __expf(20.f*s.x), x1 = __expf(20.f*s.y);
    float x2 = __expf(20.f*s.z), x3 = __expf(20.f*s.w);
    float E0 = x0*r0, E1 = x1*r1, E2 = x2*r2, E3 = x3*r3;
    float cf = 1.f / ((E0+E1+E2+E3) * 65536.f);
    if (mode == 1) { a0 += x0*cf; a1 += x1*cf; a2 += x2*cf; a3 += x3*cf; }
    else {
      float term = (E0*s.x + E1*s.y + E2*s.z + E3*s.w) * 65536.f * cf;
      float mx = fmaxf(fmaxf(s.x,s.y), fmaxf(s.z,s.w));
      float z = __expf(s.x-mx)+__expf(s.y-mx)+__expf(s.z-mx)+__expf(s.w-mx);
      lsum += (mx + logf(z)) - term;
    }
  }
  int lane = threadIdx.x & 63;
  if (mode == 1) {
    a0 = wredsum(a0); a1 = wredsum(a1); a2 = wredsum(a2); a3 = wredsum(a3);
    if (lane == 0) {
      atomicAdd(&Rout[0], a0); atomicAdd(&Rout[1], a1);
      atomicAdd(&Rout[2], a2); atomicAdd(&Rout[3], a3);
    }
  } else {
    lsum = wredsum(lsum);
    if (lane == 0) atomicAdd(lossAcc, lsum);
  }
}

// ---------------- bf16 GEMM 128x128x64 on RAW bf16 inputs; epilogue scales by invU*invP,
// writes bf16 sim + per-column sum of exp(20 s)
__global__ __launch_bounds__(256) void k_gemm(const unsigned short* __restrict__ A,
                                              const unsigned short* __restrict__ B,
                                              const float* __restrict__ invU,
                                              const float* __restrict__ invP,
                                              unsigned short* __restrict__ S,
                                              float* __restrict__ R1) {
  __shared__ unsigned short lAB[16384]; // A[128][64] + B[128][64]; reused as C[128][128]
  __shared__ float red[512];
  unsigned short* lA = lAB;
  unsigned short* lB = lAB + 8192;
  const int bid = blockIdx.x;
  const int rowblk = bid >> 3, colblk = bid & 7;
  const int tid = threadIdx.x, lane = tid & 63;
  const int wid = tid >> 6, wm = wid >> 1, wn = wid & 1;
  f32x4 acc[4][4];
  #pragma unroll
  for (int m = 0; m < 4; m++)
    #pragma unroll
    for (int n = 0; n < 4; n++) acc[m][n] = (f32x4){0.f,0.f,0.f,0.f};
  const unsigned short* Ag = A + (size_t)rowblk * 128 * GK;
  const unsigned short* Bg = B + (size_t)colblk * 128 * GK;
  const int r0 = tid >> 3, c0 = (tid & 7) * 8;
  for (int kt = 0; kt < GK; kt += 64) {
    #pragma unroll
    for (int i = 0; i < 4; i++)
      GLL(Ag + (size_t)(r0 + i*32) * GK + kt + c0, lA + (i*256 + tid) * 8);
    #pragma unroll
    for (int i = 0; i < 4; i++)
      GLL(Bg + (size_t)(r0 + i*32) * GK + kt + c0, lB + (i*256 + tid) * 8);
    __syncthreads();
    #pragma unroll
    for (int kk = 0; kk < 2; kk++) {
      short8 af[4], bf[4];
      #pragma unroll
      for (int m = 0; m < 4; m++)
        af[m] = *(const short8*)(lA + (wm*64 + m*16 + (lane & 15)) * 64 + kk*32 + (lane >> 4) * 8);
      #pragma unroll
      for (int n = 0; n < 4; n++)
        bf[n] = *(const short8*)(lB + (wn*64 + n*16 + (lane & 15)) * 64 + kk*32 + (lane >> 4) * 8);
      #pragma unroll
      for (int m = 0; m < 4; m++)
        #pragma unroll
        for (int n = 0; n < 4; n++)
          acc[m][n] = __builtin_amdgcn_mfma_f32_16x16x32_bf16(af[m], bf[n], acc[m][n], 0, 0, 0);
    }
    __syncthreads();
  }
  // epilogue: scale by invU[row]*invP[col], acc -> LDS bf16 C-tile, coalesced store + colsum exp(20 s)
  unsigned short* lC = lAB;
  #pragma unroll
  for (int m = 0; m < 4; m++)
    #pragma unroll
    for (int n = 0; n < 4; n++) {
      int col = wn*64 + n*16 + (lane & 15);
      float ip = invP[colblk * 128 + col];
      #pragma unroll
      for (int r = 0; r < 4; r++) {
        int row = wm*64 + m*16 + ((lane >> 4) << 2) + r;
        float iu = invU[rowblk * 128 + row];
        lC[row * 128 + col] = f2bf(acc[m][n][r] * iu * ip);
      }
    }
  __syncthreads();
  float racc[8];
  #pragma unroll
  for (int j = 0; j < 8; j++) racc[j] = 0.f;
  const size_t outbase = (size_t)rowblk * 128 * GN + (size_t)colblk * 128;
  #pragma unroll
  for (int i = 0; i < 8; i++) {
    int chunk = i * 256 + tid;
    int row = chunk >> 4, cc = chunk & 15;
    short8 v = *(const short8*)(lC + chunk * 8);
    *(short8*)(S + outbase + (size_t)row * GN + cc * 8) = v;
    #pragma unroll
    for (int j = 0; j < 8; j++)
      racc[j] += __expf(20.f * bf2f((unsigned short)v[j]));
  }
  #pragma unroll
  for (int j = 0; j < 8; j++) {
    racc[j] += __shfl_xor(racc[j], 16);
    racc[j] += __shfl_xor(racc[j], 32);
  }
  if (lane < 16) {
    #pragma unroll
    for (int j = 0; j < 8; j++) red[wid * 128 + lane * 8 + j] = racc[j];
  }
  __syncthreads();
  if (tid < 128) {
    float s4 = red[tid] + red[128 + tid] + red[256 + tid] + red[384 + tid];
    atomicAdd(&R1[colblk * 128 + tid], s4);
  }
}

// ---------------- big sinkhorn pass over sim bf16 [65536][1024]
__global__ __launch_bounds__(256) void k_sink(const unsigned short* __restrict__ S,
                                              const float* __restrict__ Rin,
                                              float* __restrict__ Rout, float* __restrict__ lossAcc, int mode) {
  __shared__ float lds[4096];
  int tid = threadIdx.x, lane = tid & 63, w = tid >> 6;
  float rj[16];
  #pragma unroll
  for (int j = 0; j < 16; j++) rj[j] = 1.f / (1024.f * Rin[lane*16 + j]);
  float acc[16];
  #pragma unroll
  for (int j = 0; j < 16; j++) acc[j] = 0.f;
  float lsum = 0.f;
  int row0 = blockIdx.x * 256;
  for (int rr = w; rr < 256; rr += 4) {
    int row = row0 + rr;
    const unsigned short* Sr = S + (size_t)row * 1024 + lane * 16;
    ushort8 v0 = *(const ushort8*)Sr;
    ushort8 v1 = *(const ushort8*)(Sr + 8);
    float s[16], X[16], E[16];
    #pragma unroll
    for (int j = 0; j < 8; j++) { s[j] = bf2f(v0[j]); s[8+j] = bf2f(v1[j]); }
    float cs = 0.f;
    #pragma unroll
    for (int j = 0; j < 16; j++) { X[j] = __expf(20.f*s[j]); E[j] = X[j] * rj[j]; cs += E[j]; }
    cs = wredsum(cs);
    float cf = 1.f / (cs * 65536.f);
    if (mode == 1) {
      #pragma unroll
      for (int j = 0; j < 16; j++) acc[j] += X[j] * cf;
    } else {
      float term = 0.f, mx = -1e30f;
      #pragma unroll
      for (int j = 0; j < 16; j++) { term += E[j]*s[j]; mx = fmaxf(mx, s[j]); }
      term = wredsum(term);
      mx = fmaxf(mx, __shfl_xor(mx, 32)); mx = fmaxf(mx, __shfl_xor(mx, 16));
      mx = fmaxf(mx, __shfl_xor(mx, 8));  mx = fmaxf(mx, __shfl_xor(mx, 4));
      mx = fmaxf(mx, __shfl_xor(mx, 2));  mx = fmaxf(mx, __shfl_xor(mx, 1));
      float z = 0.f;
      #pragma unroll
      for (int j = 0; j < 16; j++) z += __expf(10.f*(s[j] - mx));
      z = wredsum(z);
      if (lane == 0) lsum += (10.f*mx + logf(z)) - term * (10.f * 65536.f * cf);
    }
  }
  if (mode == 1) {
    #pragma unroll
    for (int j = 0; j < 16; j++) lds[w*1024 + lane + 64*j] = acc[j];
    __syncthreads();
    for (int q = tid; q < 1024; q += 256) {
      float s4 = lds[q] + lds[1024+q] + lds[2048+q] + lds[3072+q];
      atomicAdd(&Rout[(q & 63)*16 + (q >> 6)], s4);
    }
  } else {
    if (lane == 0) lds[w] = lsum;
    __syncthreads();
    if (tid == 0) atomicAdd(lossAcc, lds[0]+lds[1]+lds[2]+lds[3]);
  }
}

// ---------------- finalize 5 FLOAT32 outputs (reference output dtype is float32!)
__global__ void k_final(const float* __restrict__ scal, float* __restrict__ out) {
  if (threadIdx.x == 0 && blockIdx.x == 0) {
    float l   = 1.f - scal[0] / 16384.f;
    float ln  = scal[1] / 32768.f;
    float lp  = scal[2] / 65536.f;
    float ul  = scal[3] / 65536.f;
    float rep = scal[4];
    float nl  = 0.5f * (ln + lp);
    float cls = 0.45f*l + 0.3f*nl + 0.1f*ul + 0.15f*rep;
    out[0] = cls;
    out[1] = l;
    out[2] = ul;
    out[3] = nl;
    out[4] = rep;
  }
}

extern "C" void kernel_launch(void* const* d_in, const int* in_sizes, int n_in,
                              void* d_out, int out_size, void* d_ws, size_t ws_size,
                              hipStream_t stream) {
  const float* PF = (const float*)d_in[0];   // p_feats [16384][512]
  const float* UF = (const float*)d_in[1];   // u_feats [65536][512]
  const float* NF = (const float*)d_in[2];   // n_feats [32768][512]
  const float* PC = (const float*)d_in[3];   // positive_center [1][512]
  const float* PU = (const float*)d_in[4];   // proxy_u [1024][512]
  const float* NC = (const float*)d_in[5];   // negative_centers [4][512]

  char* ws = (char*)d_ws;
  const size_t WS_REQUIRED = 203606528ULL;
  if (ws_size < WS_REQUIRED) return;

  // zeroed accumulator region [0, 20608)
  float* R1     = (float*)(ws + 0);        // 1024
  float* R2     = (float*)(ws + 4096);     // 1024
  float* R3     = (float*)(ws + 8192);     // 1024
  float* R1p    = (float*)(ws + 12288);    // 4
  float* R2p    = (float*)(ws + 12304);    // 4
  float* R3p    = (float*)(ws + 12320);    // 4
  float* counts = (float*)(ws + 12336);    // 4
  float* scal   = (float*)(ws + 12352);    // [0]=p dotsum [1]=nloss [2]=pseudo [3]=uloss [4]=repulsion
  float* sums   = (float*)(ws + 12416);    // 4*512
  float* invP   = (float*)(ws + 20608);    // 1024 f32
  // scratch
  float* pos_hat   = (float*)(ws + 33280);
  float* negc0_hat = (float*)(ws + 35328);
  float* negc_hat  = (float*)(ws + 43520);
  float* inv_n     = (float*)(ws + 51712);      // 32768 f32
  float* SU        = (float*)(ws + 182784);     // [65536][4] f32 — dead after k_psink
  float* invU      = (float*)(ws + 182784);     // 65536 f32, ALIASES SU (written after psink)
  unsigned short* Ph = (unsigned short*)(ws + 1231360);   // [1024][512] raw bf16
  unsigned short* Uh = (unsigned short*)(ws + 2279936);   // [65536][512] raw bf16
  unsigned short* S  = (unsigned short*)(ws + 69388800);  // [65536][1024] bf16

  hipMemsetAsync(ws, 0, 20608, stream);

  k_prep<<<1, 320, 0, stream>>>(PC, NC, pos_hat, negc0_hat);
  k_ploss<<<64, 256, 0, stream>>>(PF, pos_hat, scal);
  k_nstats<<<128, 256, 0, stream>>>(NF, pos_hat, negc0_hat, inv_n, counts, sums);
  k_center<<<1, 256, 0, stream>>>(counts, sums, NC, pos_hat, negc_hat, scal);
  k_nloss<<<128, 256, 0, stream>>>(NF, inv_n, negc_hat, scal);
  k_upass<<<256, 256, 0, stream>>>(UF, negc_hat, SU, R1p);

  // pseudo sinkhorn (K=4): rowsum1 in k_upass -> [col1+row2] -> [col2+row3] -> [col3+loss]
  k_psink<<<128, 256, 0, stream>>>(SU, R1p, R2p, nullptr, 1);
  k_psink<<<128, 256, 0, stream>>>(SU, R2p, R3p, nullptr, 1);
  k_psink<<<128, 256, 0, stream>>>(SU, R3p, nullptr, scal + 2, 2);

  // raw bf16 + row norms (invU aliases SU: only after psink passes are done)
  k_rownorm<<<256, 256, 0, stream>>>(UF, Uh, invU, 65536);
  k_rownorm<<<4, 256, 0, stream>>>(PU, Ph, invP, 1024);

  // u branch: bf16 GEMM on raw inputs, normalized in epilogue + 3 fused sinkhorn passes
  k_gemm<<<4096, 256, 0, stream>>>(Uh, Ph, invU, invP, S, R1);
  k_sink<<<256, 256, 0, stream>>>(S, R1, R2, nullptr, 1);
  k_sink<<<256, 256, 0, stream>>>(S, R2, R3, nullptr, 1);
  k_sink<<<256, 256, 0, stream>>>(S, R3, nullptr, scal + 3, 2);

  k_final<<<1, 64, 0, stream>>>(scal, (float*)d_out);
}